// Round 8
// baseline (64.921 us; speedup 1.0000x reference)
//
#include <hip/hip_runtime.h>
#include <hip/hip_fp16.h>

#define BB 32
#define SS 2048
#define VV 516
#define NBS (BB * SS)      // 65536
#define NCHUNK 16
#define NPART 256          // comb block count
#define BUFE (8 * 2048)    // halves per staging buffer

struct alignas(8) h4 { __half2 a, b; };

__device__ inline float waveReduceSum(float v) {
    #pragma unroll
    for (int o = 32; o > 0; o >>= 1) v += __shfl_down(v, o, 64);
    return v;
}

// One block per (b, v-chunk), 512 threads (8 waves).  Single HBM sweep.
// Double REGISTER buffers (vbA/vbB) + double LDS buffers: per sub-chunk k,
//   issue loads(k+1) FIRST (stay in flight across everything below),
//   finish(k): exp prefetched regs -> fp16 LDS buf[k&1] + row-sum,
//   lgkmcnt(0); raw s_barrier   (NO vmcnt drain -> prefetch survives),
//   phase2(k): batch-read 8 rows from LDS, accumulate sum/argmax/target.
// Buffer parity: finish(k+2) rewrites buf[k&1] one barrier after phase2(k)
// finished reading it -> race-free with ONE barrier per sub-chunk.
__global__ __launch_bounds__(512, 4) void hl_tile(const float* __restrict__ x,
                                                  const int* __restrict__ target,
                                                  int* __restrict__ ctr,
                                                  float* __restrict__ pSum,
                                                  float* __restrict__ pBest,
                                                  int* __restrict__ pIdx,
                                                  float* __restrict__ xtArr) {
    __shared__ __half ldsE[2 * BUFE];     // 64 KB
    __shared__ float sRcp[2][8];

    if (blockIdx.x == 0 && threadIdx.x == 0) ctr[0] = 0;   // comb finalize ctr

    const int c = blockIdx.x & 15, b = blockIdx.x >> 4;
    const int v0 = 32 * c + (c > 12 ? c - 12 : 0);          // 12x32 + 4x33
    const int nv = (c >= 12) ? 33 : 32;
    const int nsub = (nv + 7) >> 3;                         // 4 or 5
    const int tid = threadIdx.x, lane = tid & 63, wv = tid >> 6;
    const int s0 = tid << 2;
    const int bs = b * SS + s0;

    int4 tg4 = *(const int4*)(target + bs);
    int tg[4] = {tg4.x, tg4.y, tg4.z, tg4.w};

    float sum[4]  = {0.f, 0.f, 0.f, 0.f};
    float best[4] = {-1.f, -1.f, -1.f, -1.f};
    float xt[4]   = {0.f, 0.f, 0.f, 0.f};
    int   bi[4]   = {v0, v0, v0, v0};

    const float* xb = x + (size_t)(b * VV + v0) * SS;

    float4 vbA[8], vbB[8];
    {   // prologue: prefetch sub-chunk 0 (m0 == 8, all waves)
        const float* row = xb + (size_t)wv * SS;
        #pragma unroll
        for (int j = 0; j < 8; ++j)
            vbA[j] = *(const float4*)(row + j * 256 + lane * 4);
    }

    auto body = [&](int k, float4 (&cur)[8], float4 (&nxt)[8]) {
        const int m = (nv - k * 8 < 8) ? (nv - k * 8) : 8;
        const int kb = k & 1;
        // ---- issue prefetch(k+1) FIRST: in flight under finish+barrier+phase2
        if (k + 1 < nsub) {
            const int m2 = nv - (k + 1) * 8;
            if (wv < m2) {                                  // wave-uniform
                const float* row = xb + (size_t)((k + 1) * 8 + wv) * SS;
                #pragma unroll
                for (int j = 0; j < 8; ++j)
                    nxt[j] = *(const float4*)(row + j * 256 + lane * 4);
            }
        }
        // ---- finish(k): exp, fp16 pack, LDS write, row-sum ----
        if (wv < m) {
            __half* dst = ldsE + kb * BUFE + wv * 2048;
            float a0 = 0.f, a1 = 0.f, a2 = 0.f, a3 = 0.f;
            #pragma unroll
            for (int j = 0; j < 8; ++j) {
                float ex = __expf(cur[j].x), ey = __expf(cur[j].y);
                float ez = __expf(cur[j].z), ew = __expf(cur[j].w);
                h4 h;
                h.a = __halves2half2(__float2half_rn(ex), __float2half_rn(ey));
                h.b = __halves2half2(__float2half_rn(ez), __float2half_rn(ew));
                *(h4*)(dst + j * 256 + lane * 4) = h;
                a0 += ex; a1 += ey; a2 += ez; a3 += ew;
            }
            float ssum = waveReduceSum((a0 + a1) + (a2 + a3));
            if (lane == 0) sRcp[kb][wv] = 1.f / ssum;
        }
        // LDS visible cross-wave; global prefetch NOT drained:
        asm volatile("s_waitcnt lgkmcnt(0)" ::: "memory");
        __builtin_amdgcn_s_barrier();
        // ---- phase2(k): batch-read m rows, accumulate ----
        const __half* src = ldsE + kb * BUFE + s0;
        if (m == 8) {
            h4 r[8];
            #pragma unroll
            for (int i = 0; i < 8; ++i)
                r[i] = *(const h4*)(src + i * 2048);
            #pragma unroll
            for (int i = 0; i < 8; ++i) {
                float rc = sRcp[kb][i];
                int vg = v0 + k * 8 + i;
                float e0 = __low2float(r[i].a), e1 = __high2float(r[i].a);
                float e2 = __low2float(r[i].b), e3 = __high2float(r[i].b);
                sum[0] += e0; sum[1] += e1; sum[2] += e2; sum[3] += e3;
                float c0 = e0 * rc, c1 = e1 * rc, c2 = e2 * rc, c3 = e3 * rc;
                if (c0 > best[0]) { best[0] = c0; bi[0] = vg; }
                if (c1 > best[1]) { best[1] = c1; bi[1] = vg; }
                if (c2 > best[2]) { best[2] = c2; bi[2] = vg; }
                if (c3 > best[3]) { best[3] = c3; bi[3] = vg; }
            }
        } else {
            for (int v = 0; v < m; ++v) {
                h4 r = *(const h4*)(src + v * 2048);
                float rc = sRcp[kb][v];
                int vg = v0 + k * 8 + v;
                float e0 = __low2float(r.a), e1 = __high2float(r.a);
                float e2 = __low2float(r.b), e3 = __high2float(r.b);
                sum[0] += e0; sum[1] += e1; sum[2] += e2; sum[3] += e3;
                float c0 = e0 * rc, c1 = e1 * rc, c2 = e2 * rc, c3 = e3 * rc;
                if (c0 > best[0]) { best[0] = c0; bi[0] = vg; }
                if (c1 > best[1]) { best[1] = c1; bi[1] = vg; }
                if (c2 > best[2]) { best[2] = c2; bi[2] = vg; }
                if (c3 > best[3]) { best[3] = c3; bi[3] = vg; }
            }
        }
        // ---- target gather from this sub-chunk's buffer ----
        #pragma unroll
        for (int i = 0; i < 4; ++i) {
            int lr = tg[i] - (v0 + k * 8);
            if (lr >= 0 && lr < m)
                xt[i] = __logf(__half2float(ldsE[kb * BUFE + lr * 2048 + s0 + i]));
        }
        // no trailing barrier needed (buffer parity, see header comment)
    };

    for (int k = 0; k < nsub; k += 2) {
        body(k, vbA, vbB);
        if (k + 1 < nsub) body(k + 1, vbB, vbA);
    }

    // ---- write per-chunk partials ----
    int o = c * NBS + bs;
    *(float4*)(pSum + o)  = make_float4(sum[0], sum[1], sum[2], sum[3]);
    *(float4*)(pBest + o) = make_float4(best[0], best[1], best[2], best[3]);
    *(int4*)(pIdx + o)    = make_int4(bi[0], bi[1], bi[2], bi[3]);
    int v1 = v0 + nv;
    #pragma unroll
    for (int i = 0; i < 4; ++i)
        if (tg[i] >= v0 && tg[i] < v1) xtArr[bs + i] = xt[i];
}

// Merge chunk partials per (b,s); nll + penalty mask; block partial sums;
// last block folds the 256 partials into the scalar output.  (R3-proven.)
__global__ __launch_bounds__(256) void hl_comb(const int* __restrict__ target,
                                               const int* __restrict__ ttype,
                                               const float* __restrict__ tval,
                                               const float* __restrict__ coeff,
                                               const float* __restrict__ harm,
                                               const float* __restrict__ pSum,
                                               const float* __restrict__ pBest,
                                               const int* __restrict__ pIdx,
                                               const float* __restrict__ xtArr,
                                               float* __restrict__ pNll,
                                               float* __restrict__ pMask,
                                               int* __restrict__ counter,
                                               float* __restrict__ outv) {
    __shared__ float lds[8];
    __shared__ bool isLast;
    int idx = blockIdx.x * 256 + threadIdx.x;            // (b,s) flat

    float sum = 0.f, best = -1e30f;
    int bestIdx = 0;
    #pragma unroll
    for (int c = 0; c < NCHUNK; ++c) {                   // ascending: first-idx ties
        int o = c * NBS + idx;
        sum += pSum[o];
        float sc = pBest[o];
        int ii = pIdx[o];
        if (sc > best) { best = sc; bestIdx = ii; }
    }
    int tgt = target[idx];
    float nll = __logf(sum) - xtArr[idx];

    int pt = ttype[bestIdx], tt = ttype[tgt];
    float pv = tval[bestIdx], tv = tval[tgt];
    float d = fabsf(pv - tv);
    float pw = (d == 7.f) ? harm[0] : (d == 5.f) ? harm[1] : (d == 3.f) ? harm[2]
             : (d == 4.f) ? harm[3] : (d == 1.f) ? harm[4] : (d == 2.f) ? harm[5]
             : harm[6];
    float w = (pt == 0) ? pw
            : (pt == 1) ? coeff[1] * d * (1.f / 160.f)
            : (pt == 2) ? coeff[2] * d * (1.f / 100.f)
            :             coeff[3] * d * (1.f / 128.f);
    float mask = (pt != tt) ? coeff[0] : w;

    int lane = threadIdx.x & 63, wvv = threadIdx.x >> 6;
    float rn = waveReduceSum(nll);
    if (lane == 0) lds[wvv] = rn;
    __syncthreads();
    float totN = (threadIdx.x == 0) ? lds[0] + lds[1] + lds[2] + lds[3] : 0.f;
    __syncthreads();
    float rm = waveReduceSum(mask);
    if (lane == 0) lds[wvv] = rm;
    __syncthreads();
    if (threadIdx.x == 0) {
        pNll[blockIdx.x]  = totN;
        pMask[blockIdx.x] = lds[0] + lds[1] + lds[2] + lds[3];
        __threadfence();
        unsigned old = atomicAdd((unsigned*)counter, 1u);
        isLast = (old == NPART - 1);
    }
    __syncthreads();
    if (isLast) {
        __threadfence();
        int t = threadIdx.x;
        float n = waveReduceSum(pNll[t]);
        float m = waveReduceSum(pMask[t]);
        if (lane == 0) { lds[wvv] = n; lds[4 + wvv] = m; }
        __syncthreads();
        if (t == 0) {
            float tn = lds[0] + lds[1] + lds[2] + lds[3];
            float tm = lds[4] + lds[5] + lds[6] + lds[7];
            const float inv = 1.f / (float)NBS;
            outv[0] = (tn * inv) * (1.f + tm * inv);
        }
    }
}

extern "C" void kernel_launch(void* const* d_in, const int* in_sizes, int n_in,
                              void* d_out, int out_size, void* d_ws, size_t ws_size,
                              hipStream_t stream) {
    const float* x      = (const float*)d_in[0];
    const int*   target = (const int*)d_in[1];
    const int*   ttype  = (const int*)d_in[2];
    const float* tval   = (const float*)d_in[3];
    const float* coeff  = (const float*)d_in[4];
    const float* harm   = (const float*)d_in[5];

    float* ws    = (float*)d_ws;
    int*   ctr   = (int*)ws;                     // 4 ints
    float* pNll  = ws + 4;                       // 256
    float* pMask = pNll + NPART;                 // 256
    float* xtArr = pMask + NPART;                // 65536 (offset 516 -> 16B-aligned)
    float* pSum  = xtArr + NBS;                  // 16*65536
    float* pBest = pSum + (size_t)NCHUNK * NBS;  // 16*65536
    int*   pIdx  = (int*)(pBest + (size_t)NCHUNK * NBS);

    hl_tile<<<BB * NCHUNK, 512, 0, stream>>>(x, target, ctr, pSum, pBest,
                                             pIdx, xtArr);
    hl_comb<<<NBS / 256, 256, 0, stream>>>(target, ttype, tval, coeff, harm,
                                           pSum, pBest, pIdx, xtArr,
                                           pNll, pMask, ctr, (float*)d_out);
}